// Round 1
// baseline (1115.238 us; speedup 1.0000x reference)
//
#include <hip/hip_runtime.h>
#include <math.h>

namespace {

constexpr int B  = 2;
constexpr int C  = 256;
constexpr int NH = 8;
constexpr int L  = 4;
constexpr int P  = 4;
constexpr int D  = 32;     // C / NH
constexpr int LV = 13294;
constexpr int LQ = 13294;

// Levels: (100,100),(50,50),(25,25),(13,13) — all square.
constexpr int SZ[4]    = {100, 50, 25, 13};
constexpr int START[4] = {0, 10000, 12500, 13125};

// ---------------------------------------------------------------------------
// Kernel 1: val = value @ Wv + bv, stored as [B][NH][LV][D] for the sampler.
// One block per (b, i) row; q-row staged in LDS; thread t computes channel t.
// ---------------------------------------------------------------------------
__global__ __launch_bounds__(256) void k_val_proj(
    const float* __restrict__ value, const float* __restrict__ Wv,
    const float* __restrict__ bv, float* __restrict__ val) {
  const int row = blockIdx.x;           // row = b*LV + i
  const int b = row / LV, i = row % LV;
  __shared__ float vrow[C];
  const int t = threadIdx.x;
  vrow[t] = value[(i * B + b) * C + t]; // value layout (LV, B, C)
  __syncthreads();
  float acc = bv[t];
#pragma unroll 8
  for (int k = 0; k < C; ++k) acc = fmaf(vrow[k], Wv[k * C + t], acc);
  const int h = t >> 5, d = t & 31;
  val[((size_t)(b * NH + h) * LV + i) * D + d] = acc;
}

// ---------------------------------------------------------------------------
// Kernel 2: offsets + attention for one (b,q) per block.
//   - thread t computes offset column t (K=256 dot), converts to final
//     sampling location: clip(rp) + off/size[l]
//   - threads 0..127 also compute attn logits; softmax over 16 per head.
// ---------------------------------------------------------------------------
__global__ __launch_bounds__(256) void k_off_attn(
    const float* __restrict__ query, const float* __restrict__ rp,
    const float* __restrict__ Woff, const float* __restrict__ boff,
    const float* __restrict__ Wattn, const float* __restrict__ battn,
    float* __restrict__ loc_out, float* __restrict__ attn_out) {
  const int m = blockIdx.x;             // m = b*LQ + q
  const int b = m / LQ, q = m % LQ;
  __shared__ float qrow[C];
  __shared__ float logits[NH * L * P];
  const int t = threadIdx.x;
  qrow[t] = query[(q * B + b) * C + t]; // query layout (LQ, B, C)
  __syncthreads();

  // ---- offset column t ----
  float acc = boff[t];
#pragma unroll 8
  for (int k = 0; k < C; ++k) acc = fmaf(qrow[k], Woff[k * (NH * L * P * 2) + t], acc);
  // t = ((h*L + l)*P + p)*2 + xy
  const int xy = t & 1;
  const int l  = (t >> 3) & 3;
  float r = rp[((size_t)(b * LQ + q) * L + l) * 2 + xy];
  r = fminf(fmaxf(r, 1e-5f), 1.0f - 1e-5f);
  const float sz = (l == 0) ? 100.f : (l == 1) ? 50.f : (l == 2) ? 25.f : 13.f;
  loc_out[(size_t)m * 256 + t] = r + acc / sz;

  // ---- attention logits ----
  if (t < NH * L * P) {
    float a = battn[t];
#pragma unroll 8
    for (int k = 0; k < C; ++k) a = fmaf(qrow[k], Wattn[k * (NH * L * P) + t], a);
    logits[t] = a;
  }
  __syncthreads();

  // ---- per-head softmax over L*P = 16 ----
  if (t < NH) {
    float mx = -1e30f;
#pragma unroll
    for (int j = 0; j < 16; ++j) mx = fmaxf(mx, logits[t * 16 + j]);
    float e[16];
    float s = 0.f;
#pragma unroll
    for (int j = 0; j < 16; ++j) {
      e[j] = __expf(logits[t * 16 + j] - mx);
      s += e[j];
    }
    const float inv = 1.0f / s;
#pragma unroll
    for (int j = 0; j < 16; ++j)
      attn_out[(size_t)m * 128 + t * 16 + j] = e[j] * inv;
  }
}

// ---------------------------------------------------------------------------
// Kernel 3: bilinear sampling + attention weighting.
// One block per (b,q); thread t -> head h = t>>5, channel d = t&31.
// 16 (l,p) points, 4-corner bilinear with zero padding.
// ---------------------------------------------------------------------------
__global__ __launch_bounds__(256) void k_sample(
    const float* __restrict__ val, const float* __restrict__ loc,
    const float* __restrict__ attn, float* __restrict__ tmp) {
  const int m = blockIdx.x;             // b*LQ + q
  const int b = m / LQ;
  __shared__ float sloc[256];
  __shared__ float sattn[128];
  const int t = threadIdx.x;
  sloc[t] = loc[(size_t)m * 256 + t];
  if (t < 128) sattn[t] = attn[(size_t)m * 128 + t];
  __syncthreads();

  const int h = t >> 5, d = t & 31;
  const float* vbase = val + ((size_t)(b * NH + h) * LV) * D + d;
  float acc = 0.f;
#pragma unroll
  for (int l = 0; l < L; ++l) {
    const int Hl = SZ[l], Wl = SZ[l];
    const float* vlev = vbase + (size_t)START[l] * D;
#pragma unroll
    for (int p = 0; p < P; ++p) {
      const int base = ((h * L + l) * P + p) * 2;
      const float x = sloc[base] * (float)Wl - 0.5f;
      const float y = sloc[base + 1] * (float)Hl - 0.5f;
      const float x0f = floorf(x), y0f = floorf(y);
      const float wx = x - x0f, wy = y - y0f;
      const int x0 = (int)x0f, y0 = (int)y0f;
      const float aw = sattn[(h * L + l) * P + p];
      float sample = 0.f;
#pragma unroll
      for (int dy = 0; dy < 2; ++dy) {
        const int yi = y0 + dy;
        if (yi < 0 || yi >= Hl) continue;
        const float wyc = dy ? wy : 1.f - wy;
#pragma unroll
        for (int dx = 0; dx < 2; ++dx) {
          const int xi = x0 + dx;
          if (xi < 0 || xi >= Wl) continue;
          const float w = wyc * (dx ? wx : 1.f - wx);
          sample = fmaf(w, vlev[((size_t)yi * Wl + xi) * D], sample);
        }
      }
      acc = fmaf(aw, sample, acc);
    }
  }
  tmp[(size_t)m * C + t] = acc;         // t == h*32+d == channel
}

// ---------------------------------------------------------------------------
// Kernel 4: out = tmp @ Wo + bo + query, stored in (LQ, B, C) layout.
// ---------------------------------------------------------------------------
__global__ __launch_bounds__(256) void k_out_proj(
    const float* __restrict__ tmp, const float* __restrict__ Wo,
    const float* __restrict__ bo, const float* __restrict__ query,
    float* __restrict__ out) {
  const int m = blockIdx.x;             // b*LQ + q
  const int b = m / LQ, q = m % LQ;
  __shared__ float trow[C];
  const int t = threadIdx.x;
  trow[t] = tmp[(size_t)m * C + t];
  __syncthreads();
  float acc = bo[t];
#pragma unroll 8
  for (int k = 0; k < C; ++k) acc = fmaf(trow[k], Wo[k * C + t], acc);
  out[(size_t)(q * B + b) * C + t] = acc + query[(size_t)(q * B + b) * C + t];
}

}  // namespace

extern "C" void kernel_launch(void* const* d_in, const int* in_sizes, int n_in,
                              void* d_out, int out_size, void* d_ws, size_t ws_size,
                              hipStream_t stream) {
  const float* query = (const float*)d_in[0];
  const float* rp    = (const float*)d_in[1];
  const float* value = (const float*)d_in[2];
  // d_in[3] spatial_shapes, d_in[4] level_start_index: compile-time constants.
  const float* Wv    = (const float*)d_in[5];
  const float* bv    = (const float*)d_in[6];
  const float* Woff  = (const float*)d_in[7];
  const float* boff  = (const float*)d_in[8];
  const float* Wattn = (const float*)d_in[9];
  const float* battn = (const float*)d_in[10];
  const float* Wo    = (const float*)d_in[11];
  const float* bo    = (const float*)d_in[12];
  float* out = (float*)d_out;

  float* ws   = (float*)d_ws;
  float* val  = ws;                                   // B*NH*LV*D   = 6,806,528 f
  float* loc  = val + (size_t)B * NH * LV * D;        // B*LQ*256    = 6,806,528 f
  float* attn = loc + (size_t)B * LQ * NH * L * P * 2; // B*LQ*128   = 3,403,264 f
  float* tmp  = attn + (size_t)B * LQ * NH * L * P;   // B*LQ*C      = 6,806,528 f

  k_val_proj<<<B * LV, 256, 0, stream>>>(value, Wv, bv, val);
  k_off_attn<<<B * LQ, 256, 0, stream>>>(query, rp, Woff, boff, Wattn, battn, loc, attn);
  k_sample<<<B * LQ, 256, 0, stream>>>(val, loc, attn, tmp);
  k_out_proj<<<B * LQ, 256, 0, stream>>>(tmp, Wo, bo, query, out);
}

// Round 2
// 516.496 us; speedup vs baseline: 2.1592x; 2.1592x over previous
//
#include <hip/hip_runtime.h>
#include <math.h>

namespace {

typedef __attribute__((ext_vector_type(8))) short short8;
typedef __attribute__((ext_vector_type(4))) float f32x4;

constexpr int B  = 2;
constexpr int C  = 256;
constexpr int NH = 8;
constexpr int L  = 4;
constexpr int P  = 4;
constexpr int D  = 32;
constexpr int LV = 13294;
constexpr int LQ = 13294;
constexpr int M  = B * LQ;      // 26588 rows for all GEMMs

constexpr int SZ[4]    = {100, 50, 25, 13};
constexpr int START[4] = {0, 10000, 12500, 13125};

__device__ inline short bf16r(float f) {    // RTNE f32 -> bf16
  unsigned u = __float_as_uint(f);
  u += 0x7fff + ((u >> 16) & 1);
  return (short)(u >> 16);
}

// Load one wave's A fragments: 16 rows x 256 k held in registers (8 ksteps).
// arow already points at this lane's row + quad*8.
__device__ inline void load_a(const float* __restrict__ arow, short8 a[8]) {
#pragma unroll
  for (int s = 0; s < 8; ++s) {
    const f32x4 f0 = *reinterpret_cast<const f32x4*>(arow + s * 32);
    const f32x4 f1 = *reinterpret_cast<const f32x4*>(arow + s * 32 + 4);
    short8 v;
    v[0] = bf16r(f0[0]); v[1] = bf16r(f0[1]); v[2] = bf16r(f0[2]); v[3] = bf16r(f0[3]);
    v[4] = bf16r(f1[0]); v[5] = bf16r(f1[1]); v[6] = bf16r(f1[2]); v[7] = bf16r(f1[3]);
    a[s] = v;
  }
}

// One 16(M)x16(N) output tile over K=256: 8 MFMA steps.
// btlane points at Bt row n (this lane's col) + quad*8.
__device__ inline f32x4 tile_mm(const unsigned short* __restrict__ btlane,
                                const short8 a[8]) {
  short8 b[8];
#pragma unroll
  for (int s = 0; s < 8; ++s)
    b[s] = *reinterpret_cast<const short8*>(btlane + s * 32);
  f32x4 acc = {0.f, 0.f, 0.f, 0.f};
#pragma unroll
  for (int s = 0; s < 8; ++s)
    acc = __builtin_amdgcn_mfma_f32_16x16x32_bf16(a[s], b[s], acc, 0, 0, 0);
  return acc;
}

// ---------------------------------------------------------------------------
// Weight prep: transpose + bf16-convert all weight matrices into [n][k] rows.
// grid = 896 rows (256 Wv | 256 Woff | 128 Wattn | 256 Wo), block = 256 (k).
// ---------------------------------------------------------------------------
__global__ __launch_bounds__(256) void k_prep(
    const float* __restrict__ Wv, const float* __restrict__ Woff,
    const float* __restrict__ Wattn, const float* __restrict__ Wo,
    unsigned short* __restrict__ Btv, unsigned short* __restrict__ Btoa,
    unsigned short* __restrict__ Bto) {
  const int r = blockIdx.x, k = threadIdx.x;
  if (r < 256)       Btv[r * 256 + k]            = (unsigned short)bf16r(Wv[k * 256 + r]);
  else if (r < 512)  Btoa[(r - 256) * 256 + k]   = (unsigned short)bf16r(Woff[k * 256 + (r - 256)]);
  else if (r < 640)  Btoa[(256 + r - 512) * 256 + k] = (unsigned short)bf16r(Wattn[k * 128 + (r - 512)]);
  else               Bto[(r - 640) * 256 + k]    = (unsigned short)bf16r(Wo[k * 256 + (r - 640)]);
}

// ---------------------------------------------------------------------------
// GEMM 1: val = value @ Wv + bv  -> [B][NH][LV][D]
// ---------------------------------------------------------------------------
__global__ __launch_bounds__(256) void k_gemm_val(
    const float* __restrict__ value, const unsigned short* __restrict__ Bt,
    const float* __restrict__ bv, float* __restrict__ val) {
  const int wave = (blockIdx.x << 2) + (threadIdx.x >> 6);
  const int lane = threadIdx.x & 63, quad = lane >> 4, lo = lane & 15;
  const int m0 = wave << 4;
  int mr = m0 + lo; if (mr >= M) mr = M - 1;
  const int br = mr / LV, ir = mr - br * LV;
  short8 a[8];
  load_a(value + ((size_t)(ir * B + br)) * C + quad * 8, a);
  const int mbase = m0 + quad * 4;
  for (int t = 0; t < 16; ++t) {
    const int n = t * 16 + lo;
    const f32x4 acc = tile_mm(Bt + (size_t)n * 256 + quad * 8, a);
    const float bias = bv[n];
    const int h = n >> 5, d = n & 31;
#pragma unroll
    for (int r = 0; r < 4; ++r) {
      const int m = mbase + r;
      if (m < M) {
        const int b = m / LV, i = m - b * LV;
        val[(((size_t)(b * NH + h)) * LV + i) * D + d] = acc[r] + bias;
      }
    }
  }
}

// ---------------------------------------------------------------------------
// GEMM 2: offsets (256 cols -> sampling locations) + attn logits (128 cols
// -> softmaxed weights). N-tiles 0..15 offsets, 16..23 attn (head = t-16).
// ---------------------------------------------------------------------------
__global__ __launch_bounds__(256) void k_gemm_offattn(
    const float* __restrict__ query, const float* __restrict__ rp,
    const unsigned short* __restrict__ Bt, const float* __restrict__ boff,
    const float* __restrict__ battn, float* __restrict__ loc,
    float* __restrict__ attn) {
  const int wave = (blockIdx.x << 2) + (threadIdx.x >> 6);
  const int lane = threadIdx.x & 63, quad = lane >> 4, lo = lane & 15;
  const int m0 = wave << 4;
  int mr = m0 + lo; if (mr >= M) mr = M - 1;
  const int br = mr / LQ, qr = mr - br * LQ;
  short8 a[8];
  load_a(query + ((size_t)(qr * B + br)) * C + quad * 8, a);
  const int mbase = m0 + quad * 4;
  for (int t = 0; t < 24; ++t) {
    const int n = t * 16 + lo;
    const f32x4 acc = tile_mm(Bt + (size_t)n * 256 + quad * 8, a);
    if (t < 16) {
      // offset col n = h*32 + l*8 + p*2 + xy
      const int xy = n & 1, l = (n >> 3) & 3;
      const float sz = (l == 0) ? 100.f : (l == 1) ? 50.f : (l == 2) ? 25.f : 13.f;
      const float bias = boff[n];
#pragma unroll
      for (int r = 0; r < 4; ++r) {
        const int m = mbase + r;
        if (m < M) {
          float rv = rp[(size_t)m * 8 + l * 2 + xy];
          rv = fminf(fmaxf(rv, 1e-5f), 1.f - 1e-5f);
          loc[(size_t)m * 256 + n] = rv + (acc[r] + bias) / sz;
        }
      }
    } else {
      const int n2 = (t - 16) * 16 + lo;   // head*16 + col
      const float bias = battn[n2];
#pragma unroll
      for (int r = 0; r < 4; ++r) {
        float v = acc[r] + bias;
        // softmax over the 16 cols of this head: lanes within the quad
        float mx = v;
#pragma unroll
        for (int msk = 8; msk >= 1; msk >>= 1) mx = fmaxf(mx, __shfl_xor(mx, msk, 64));
        const float e = __expf(v - mx);
        float s = e;
#pragma unroll
        for (int msk = 8; msk >= 1; msk >>= 1) s += __shfl_xor(s, msk, 64);
        const int m = mbase + r;
        if (m < M) attn[(size_t)m * 128 + n2] = e / s;
      }
    }
  }
}

// ---------------------------------------------------------------------------
// Bilinear sampling + attention weighting (unchanged from R1).
// NOTE: loc is fully staged into LDS before tmp is written, so tmp may alias loc.
// ---------------------------------------------------------------------------
__global__ __launch_bounds__(256) void k_sample(
    const float* __restrict__ val, const float* __restrict__ loc,
    const float* __restrict__ attn, float* __restrict__ tmp) {
  const int m = blockIdx.x;
  const int b = m / LQ;
  __shared__ float sloc[256];
  __shared__ float sattn[128];
  const int t = threadIdx.x;
  sloc[t] = loc[(size_t)m * 256 + t];
  if (t < 128) sattn[t] = attn[(size_t)m * 128 + t];
  __syncthreads();

  const int h = t >> 5, d = t & 31;
  const float* vbase = val + ((size_t)(b * NH + h) * LV) * D + d;
  float acc = 0.f;
#pragma unroll
  for (int l = 0; l < L; ++l) {
    const int Hl = SZ[l], Wl = SZ[l];
    const float* vlev = vbase + (size_t)START[l] * D;
#pragma unroll
    for (int p = 0; p < P; ++p) {
      const int base = ((h * L + l) * P + p) * 2;
      const float x = sloc[base] * (float)Wl - 0.5f;
      const float y = sloc[base + 1] * (float)Hl - 0.5f;
      const float x0f = floorf(x), y0f = floorf(y);
      const float wx = x - x0f, wy = y - y0f;
      const int x0 = (int)x0f, y0 = (int)y0f;
      const float aw = sattn[(h * L + l) * P + p];
      float sample = 0.f;
#pragma unroll
      for (int dy = 0; dy < 2; ++dy) {
        const int yi = y0 + dy;
        if (yi < 0 || yi >= Hl) continue;
        const float wyc = dy ? wy : 1.f - wy;
#pragma unroll
        for (int dx = 0; dx < 2; ++dx) {
          const int xi = x0 + dx;
          if (xi < 0 || xi >= Wl) continue;
          const float w = wyc * (dx ? wx : 1.f - wx);
          sample = fmaf(w, vlev[((size_t)yi * Wl + xi) * D], sample);
        }
      }
      acc = fmaf(aw, sample, acc);
    }
  }
  tmp[(size_t)m * C + t] = acc;
}

// ---------------------------------------------------------------------------
// GEMM 3: out = tmp @ Wo + bo + query, stored (LQ, B, C).
// ---------------------------------------------------------------------------
__global__ __launch_bounds__(256) void k_gemm_out(
    const float* __restrict__ tmp, const float* __restrict__ query,
    const unsigned short* __restrict__ Bt, const float* __restrict__ bo,
    float* __restrict__ out) {
  const int wave = (blockIdx.x << 2) + (threadIdx.x >> 6);
  const int lane = threadIdx.x & 63, quad = lane >> 4, lo = lane & 15;
  const int m0 = wave << 4;
  int mr = m0 + lo; if (mr >= M) mr = M - 1;
  short8 a[8];
  load_a(tmp + (size_t)mr * C + quad * 8, a);
  const int mbase = m0 + quad * 4;
  for (int t = 0; t < 16; ++t) {
    const int n = t * 16 + lo;
    const f32x4 acc = tile_mm(Bt + (size_t)n * 256 + quad * 8, a);
    const float bias = bo[n];
#pragma unroll
    for (int r = 0; r < 4; ++r) {
      const int m = mbase + r;
      if (m < M) {
        const int b = m / LQ, q = m - b * LQ;
        const size_t o = ((size_t)(q * B + b)) * C + n;
        out[o] = acc[r] + bias + query[o];
      }
    }
  }
}

}  // namespace

extern "C" void kernel_launch(void* const* d_in, const int* in_sizes, int n_in,
                              void* d_out, int out_size, void* d_ws, size_t ws_size,
                              hipStream_t stream) {
  const float* query = (const float*)d_in[0];
  const float* rp    = (const float*)d_in[1];
  const float* value = (const float*)d_in[2];
  const float* Wv    = (const float*)d_in[5];
  const float* bv    = (const float*)d_in[6];
  const float* Woff  = (const float*)d_in[7];
  const float* boff  = (const float*)d_in[8];
  const float* Wattn = (const float*)d_in[9];
  const float* battn = (const float*)d_in[10];
  const float* Wo    = (const float*)d_in[11];
  const float* bo    = (const float*)d_in[12];
  float* out = (float*)d_out;

  unsigned short* Btv  = (unsigned short*)d_ws;        // 256*256
  unsigned short* Btoa = Btv + 256 * 256;              // 384*256
  unsigned short* Bto  = Btoa + 384 * 256;             // 256*256
  float* fbase = (float*)(Bto + 256 * 256);            // 16B-aligned (448 KB in)
  float* val   = fbase;                                // B*NH*LV*D = 6,806,528 f
  float* loc   = val + (size_t)B * NH * LV * D;        // B*LQ*256 (aliased by tmp)
  float* attn  = loc + (size_t)B * LQ * 256;           // B*LQ*128
  float* tmp   = loc;                                  // alias: safe, see k_sample

  const int gemm_blocks = (M + 63) / 64;               // 416

  k_prep<<<896, 256, 0, stream>>>(Wv, Woff, Wattn, Wo, Btv, Btoa, Bto);
  k_gemm_val<<<gemm_blocks, 256, 0, stream>>>(value, Btv, bv, val);
  k_gemm_offattn<<<gemm_blocks, 256, 0, stream>>>(query, rp, Btoa, boff, battn, loc, attn);
  k_sample<<<B * LQ, 256, 0, stream>>>(val, loc, attn, tmp);
  k_gemm_out<<<gemm_blocks, 256, 0, stream>>>(tmp, query, Bto, bo, out);
}

// Round 3
// 479.531 us; speedup vs baseline: 2.3257x; 1.0771x over previous
//
#include <hip/hip_runtime.h>
#include <math.h>

namespace {

typedef __attribute__((ext_vector_type(8))) short short8;
typedef __attribute__((ext_vector_type(4))) float f32x4;

constexpr int B  = 2;
constexpr int C  = 256;
constexpr int NH = 8;
constexpr int L  = 4;
constexpr int P  = 4;
constexpr int D  = 32;
constexpr int LV = 13294;
constexpr int LQ = 13294;
constexpr int M  = B * LQ;      // 26588 rows for all GEMMs

constexpr int SZ[4]    = {100, 50, 25, 13};
constexpr int START[4] = {0, 10000, 12500, 13125};

__device__ inline short bf16r(float f) {    // RTNE f32 -> bf16
  unsigned u = __float_as_uint(f);
  u += 0x7fff + ((u >> 16) & 1);
  return (short)(u >> 16);
}

// Load one wave's A fragments (f32 source): 16 rows x 256 k in registers.
__device__ inline void load_a_f32(const float* __restrict__ arow, short8 a[8]) {
#pragma unroll
  for (int s = 0; s < 8; ++s) {
    const f32x4 f0 = *reinterpret_cast<const f32x4*>(arow + s * 32);
    const f32x4 f1 = *reinterpret_cast<const f32x4*>(arow + s * 32 + 4);
    short8 v;
    v[0] = bf16r(f0[0]); v[1] = bf16r(f0[1]); v[2] = bf16r(f0[2]); v[3] = bf16r(f0[3]);
    v[4] = bf16r(f1[0]); v[5] = bf16r(f1[1]); v[6] = bf16r(f1[2]); v[7] = bf16r(f1[3]);
    a[s] = v;
  }
}

// A fragments when the source is already bf16 [m][256].
__device__ inline void load_a_bf16(const unsigned short* __restrict__ arow, short8 a[8]) {
#pragma unroll
  for (int s = 0; s < 8; ++s)
    a[s] = *reinterpret_cast<const short8*>(arow + s * 32);
}

// One 16(M)x16(N) output tile over K=256: 8 MFMA steps.
__device__ inline f32x4 tile_mm(const unsigned short* __restrict__ btlane,
                                const short8 a[8]) {
  short8 b[8];
#pragma unroll
  for (int s = 0; s < 8; ++s)
    b[s] = *reinterpret_cast<const short8*>(btlane + s * 32);
  f32x4 acc = {0.f, 0.f, 0.f, 0.f};
#pragma unroll
  for (int s = 0; s < 8; ++s)
    acc = __builtin_amdgcn_mfma_f32_16x16x32_bf16(a[s], b[s], acc, 0, 0, 0);
  return acc;
}

// ---------------------------------------------------------------------------
// Weight prep: LDS-tiled transpose + bf16 convert, W[k][n] -> Bt[n][k].
// 32x32 tiles, 256 threads. Tiles: 64 Wv | 64 Woff | 32 Wattn | 64 Wo = 224.
// ---------------------------------------------------------------------------
__global__ __launch_bounds__(256) void k_prep(
    const float* __restrict__ Wv, const float* __restrict__ Woff,
    const float* __restrict__ Wattn, const float* __restrict__ Wo,
    unsigned short* __restrict__ Btv, unsigned short* __restrict__ Btoa,
    unsigned short* __restrict__ Bto) {
  __shared__ float tile[32][33];
  const int blk = blockIdx.x;
  const float* src; unsigned short* dst; int N, local;
  if (blk < 64)       { src = Wv;    dst = Btv;             N = 256; local = blk; }
  else if (blk < 128) { src = Woff;  dst = Btoa;            N = 256; local = blk - 64; }
  else if (blk < 160) { src = Wattn; dst = Btoa + 256 * 256; N = 128; local = blk - 128; }
  else                { src = Wo;    dst = Bto;             N = 256; local = blk - 160; }
  const int ntiles = N >> 5;
  const int kt = local / ntiles, nt = local - kt * ntiles;
  const int k0 = kt << 5, n0 = nt << 5;
  const int tx = threadIdx.x & 31, ty = threadIdx.x >> 5;
#pragma unroll
  for (int r = 0; r < 4; ++r) {
    const int kk = ty + r * 8;
    tile[kk][tx] = src[(size_t)(k0 + kk) * N + n0 + tx];
  }
  __syncthreads();
#pragma unroll
  for (int r = 0; r < 4; ++r) {
    const int nn = ty + r * 8;
    dst[(size_t)(n0 + nn) * 256 + k0 + tx] = (unsigned short)bf16r(tile[tx][nn]);
  }
}

// ---------------------------------------------------------------------------
// GEMM 1: val = value @ Wv + bv  -> bf16 [B][NH][LV][D]
// ---------------------------------------------------------------------------
__global__ __launch_bounds__(256) void k_gemm_val(
    const float* __restrict__ value, const unsigned short* __restrict__ Bt,
    const float* __restrict__ bv, unsigned short* __restrict__ val) {
  const int wave = (blockIdx.x << 2) + (threadIdx.x >> 6);
  const int lane = threadIdx.x & 63, quad = lane >> 4, lo = lane & 15;
  const int m0 = wave << 4;
  int mr = m0 + lo; if (mr >= M) mr = M - 1;
  const int br = mr / LV, ir = mr - br * LV;
  short8 a[8];
  load_a_f32(value + ((size_t)(ir * B + br)) * C + quad * 8, a);
  const int mbase = m0 + quad * 4;
  for (int t = 0; t < 16; ++t) {
    const int n = t * 16 + lo;
    const f32x4 acc = tile_mm(Bt + (size_t)n * 256 + quad * 8, a);
    const float bias = bv[n];
    const int h = n >> 5, d = n & 31;
#pragma unroll
    for (int r = 0; r < 4; ++r) {
      const int m = mbase + r;
      if (m < M) {
        const int b = m / LV, i = m - b * LV;
        val[(((size_t)(b * NH + h)) * LV + i) * D + d] =
            (unsigned short)bf16r(acc[r] + bias);
      }
    }
  }
}

// ---------------------------------------------------------------------------
// GEMM 2: offsets -> sampling locations; attn logits -> softmaxed weights.
// ---------------------------------------------------------------------------
__global__ __launch_bounds__(256) void k_gemm_offattn(
    const float* __restrict__ query, const float* __restrict__ rp,
    const unsigned short* __restrict__ Bt, const float* __restrict__ boff,
    const float* __restrict__ battn, float* __restrict__ loc,
    float* __restrict__ attn) {
  const int wave = (blockIdx.x << 2) + (threadIdx.x >> 6);
  const int lane = threadIdx.x & 63, quad = lane >> 4, lo = lane & 15;
  const int m0 = wave << 4;
  int mr = m0 + lo; if (mr >= M) mr = M - 1;
  const int br = mr / LQ, qr = mr - br * LQ;
  short8 a[8];
  load_a_f32(query + ((size_t)(qr * B + br)) * C + quad * 8, a);
  const int mbase = m0 + quad * 4;
  for (int t = 0; t < 24; ++t) {
    const int n = t * 16 + lo;
    const f32x4 acc = tile_mm(Bt + (size_t)n * 256 + quad * 8, a);
    if (t < 16) {
      const int xy = n & 1, l = (n >> 3) & 3;
      const float sz = (l == 0) ? 100.f : (l == 1) ? 50.f : (l == 2) ? 25.f : 13.f;
      const float bias = boff[n];
#pragma unroll
      for (int r = 0; r < 4; ++r) {
        const int m = mbase + r;
        if (m < M) {
          float rv = rp[(size_t)m * 8 + l * 2 + xy];
          rv = fminf(fmaxf(rv, 1e-5f), 1.f - 1e-5f);
          loc[(size_t)m * 256 + n] = rv + (acc[r] + bias) / sz;
        }
      }
    } else {
      const int n2 = (t - 16) * 16 + lo;   // head*16 + col
      const float bias = battn[n2];
#pragma unroll
      for (int r = 0; r < 4; ++r) {
        float v = acc[r] + bias;
        float mx = v;
#pragma unroll
        for (int msk = 8; msk >= 1; msk >>= 1) mx = fmaxf(mx, __shfl_xor(mx, msk, 64));
        const float e = __expf(v - mx);
        float s = e;
#pragma unroll
        for (int msk = 8; msk >= 1; msk >>= 1) s += __shfl_xor(s, msk, 64);
        const int m = mbase + r;
        if (m < M) attn[(size_t)m * 128 + n2] = e / s;
      }
    }
  }
}

// ---------------------------------------------------------------------------
// Bilinear sampling + attention weighting, v2.
// 8 queries/block; 32 threads/query: thread -> (head h = s>>2, 8 channels at
// (s&3)*8). 16-B bf16x8 gathers; loc/attn staged in LDS with skewed strides
// (33/17) so the h*32-stride reads don't all land on bank 0.
// ---------------------------------------------------------------------------
__global__ __launch_bounds__(256) void k_sample(
    const unsigned short* __restrict__ val, const float* __restrict__ loc,
    const float* __restrict__ attn, unsigned short* __restrict__ tmp) {
  constexpr int QPB = 8;
  const int mblk = blockIdx.x * QPB;
  const int t = threadIdx.x;
  __shared__ float sloc[QPB * 8 * 33];    // [q][h][33]
  __shared__ float sattn[QPB * 8 * 17];   // [q][h][17]
  for (int i = t; i < QPB * 256; i += 256) {
    int mq = mblk + (i >> 8); if (mq >= M) mq = M - 1;
    const int j = i & 255;
    sloc[(((i >> 8) << 3) + (j >> 5)) * 33 + (j & 31)] = loc[(size_t)mq * 256 + j];
  }
  for (int i = t; i < QPB * 128; i += 256) {
    int mq = mblk + (i >> 7); if (mq >= M) mq = M - 1;
    const int j = i & 127;
    sattn[(((i >> 7) << 3) + (j >> 4)) * 17 + (j & 15)] = attn[(size_t)mq * 128 + j];
  }
  __syncthreads();

  const int g = t >> 5, s = t & 31, h = s >> 2, c8 = s & 3;
  const int m = mblk + g;
  const int mc = (m < M) ? m : M - 1;
  const int b = mc / LQ;
  const unsigned short* vhead = val + ((size_t)(b * NH + h) * LV) * D + c8 * 8;
  const float* ql = sloc + (g * 8 + h) * 33;
  const float* qa = sattn + (g * 8 + h) * 17;

  float acc[8] = {0.f, 0.f, 0.f, 0.f, 0.f, 0.f, 0.f, 0.f};
#pragma unroll
  for (int l = 0; l < L; ++l) {
    const int Wl = SZ[l];
    const unsigned short* vlev = vhead + (size_t)START[l] * D;
#pragma unroll
    for (int p = 0; p < P; ++p) {
      const float x = ql[l * 8 + p * 2]     * (float)Wl - 0.5f;
      const float y = ql[l * 8 + p * 2 + 1] * (float)Wl - 0.5f;
      const float aw = qa[l * 4 + p];
      const float x0f = floorf(x), y0f = floorf(y);
      const float wx = x - x0f, wy = y - y0f;
      const int x0 = (int)x0f, y0 = (int)y0f;
      const float wy1 = wy * aw, wy0 = aw - wy1;  // aw*(1-wy)
      const float wx1 = wx, wx0 = 1.f - wx;
#pragma unroll
      for (int dy = 0; dy < 2; ++dy) {
#pragma unroll
        for (int dx = 0; dx < 2; ++dx) {
          const int yi = y0 + dy, xi = x0 + dx;
          const bool ok = (xi >= 0) & (xi < Wl) & (yi >= 0) & (yi < Wl);
          const int yc = min(max(yi, 0), Wl - 1);
          const int xc = min(max(xi, 0), Wl - 1);
          const float w = ok ? (dy ? wy1 : wy0) * (dx ? wx1 : wx0) : 0.f;
          const uint4 raw = *reinterpret_cast<const uint4*>(vlev + (yc * Wl + xc) * D);
          acc[0] = fmaf(w, __uint_as_float(raw.x << 16),          acc[0]);
          acc[1] = fmaf(w, __uint_as_float(raw.x & 0xffff0000u),  acc[1]);
          acc[2] = fmaf(w, __uint_as_float(raw.y << 16),          acc[2]);
          acc[3] = fmaf(w, __uint_as_float(raw.y & 0xffff0000u),  acc[3]);
          acc[4] = fmaf(w, __uint_as_float(raw.z << 16),          acc[4]);
          acc[5] = fmaf(w, __uint_as_float(raw.z & 0xffff0000u),  acc[5]);
          acc[6] = fmaf(w, __uint_as_float(raw.w << 16),          acc[6]);
          acc[7] = fmaf(w, __uint_as_float(raw.w & 0xffff0000u),  acc[7]);
        }
      }
    }
  }
  if (m < M) {
    short8 o;
#pragma unroll
    for (int j = 0; j < 8; ++j) o[j] = bf16r(acc[j]);
    *reinterpret_cast<short8*>(tmp + (size_t)m * 256 + h * 32 + c8 * 8) = o;
  }
}

// ---------------------------------------------------------------------------
// GEMM 3: out = tmp @ Wo + bo + query, stored (LQ, B, C). tmp is bf16.
// ---------------------------------------------------------------------------
__global__ __launch_bounds__(256) void k_gemm_out(
    const unsigned short* __restrict__ tmp, const float* __restrict__ query,
    const unsigned short* __restrict__ Bt, const float* __restrict__ bo,
    float* __restrict__ out) {
  const int wave = (blockIdx.x << 2) + (threadIdx.x >> 6);
  const int lane = threadIdx.x & 63, quad = lane >> 4, lo = lane & 15;
  const int m0 = wave << 4;
  int mr = m0 + lo; if (mr >= M) mr = M - 1;
  short8 a[8];
  load_a_bf16(tmp + (size_t)mr * 256 + quad * 8, a);
  const int mbase = m0 + quad * 4;
  for (int t = 0; t < 16; ++t) {
    const int n = t * 16 + lo;
    const f32x4 acc = tile_mm(Bt + (size_t)n * 256 + quad * 8, a);
    const float bias = bo[n];
#pragma unroll
    for (int r = 0; r < 4; ++r) {
      const int m = mbase + r;
      if (m < M) {
        const int b = m / LQ, q = m - b * LQ;
        const size_t o = ((size_t)(q * B + b)) * C + n;
        out[o] = acc[r] + bias + query[o];
      }
    }
  }
}

}  // namespace

extern "C" void kernel_launch(void* const* d_in, const int* in_sizes, int n_in,
                              void* d_out, int out_size, void* d_ws, size_t ws_size,
                              hipStream_t stream) {
  const float* query = (const float*)d_in[0];
  const float* rp    = (const float*)d_in[1];
  const float* value = (const float*)d_in[2];
  const float* Wv    = (const float*)d_in[5];
  const float* bv    = (const float*)d_in[6];
  const float* Woff  = (const float*)d_in[7];
  const float* boff  = (const float*)d_in[8];
  const float* Wattn = (const float*)d_in[9];
  const float* battn = (const float*)d_in[10];
  const float* Wo    = (const float*)d_in[11];
  const float* bo    = (const float*)d_in[12];
  float* out = (float*)d_out;

  unsigned short* Btv  = (unsigned short*)d_ws;        // 256*256
  unsigned short* Btoa = Btv + 256 * 256;              // 384*256
  unsigned short* Bto  = Btoa + 384 * 256;             // 256*256
  unsigned short* val  = Bto + 256 * 256;              // B*NH*LV*D = 6,806,528 bf16
  float* loc  = (float*)(val + (size_t)B * NH * LV * D);  // M*256 f32
  float* attn = loc + (size_t)M * 256;                 // M*128 f32
  unsigned short* tmp = (unsigned short*)(attn + (size_t)M * 128);  // M*256 bf16

  const int gemm_blocks = (M + 63) / 64;               // 416
  const int sample_blocks = (M + 7) / 8;               // 3324

  k_prep<<<224, 256, 0, stream>>>(Wv, Woff, Wattn, Wo, Btv, Btoa, Bto);
  k_gemm_val<<<gemm_blocks, 256, 0, stream>>>(value, Btv, bv, val);
  k_gemm_offattn<<<gemm_blocks, 256, 0, stream>>>(query, rp, Btoa, boff, battn, loc, attn);
  k_sample<<<sample_blocks, 256, 0, stream>>>(val, loc, attn, tmp);
  k_gemm_out<<<gemm_blocks, 256, 0, stream>>>(tmp, query, Bto, bo, out);
}

// Round 4
// 319.860 us; speedup vs baseline: 3.4866x; 1.4992x over previous
//
#include <hip/hip_runtime.h>
#include <math.h>

namespace {

typedef __attribute__((ext_vector_type(8))) short short8;
typedef __attribute__((ext_vector_type(4))) float f32x4;

constexpr int B  = 2;
constexpr int C  = 256;
constexpr int NH = 8;
constexpr int L  = 4;
constexpr int P  = 4;
constexpr int D  = 32;
constexpr int LV = 13294;
constexpr int LQ = 13294;
constexpr int M  = B * LQ;      // 26588 rows for all GEMMs

constexpr int SZ[4]    = {100, 50, 25, 13};
constexpr int START[4] = {0, 10000, 12500, 13125};

__device__ inline short bf16r(float f) {    // RTNE f32 -> bf16
  unsigned u = __float_as_uint(f);
  u += 0x7fff + ((u >> 16) & 1);
  return (short)(u >> 16);
}

// Load one wave's A fragments (f32 source): 16 rows x 256 k in registers.
__device__ inline void load_a_f32(const float* __restrict__ arow, short8 a[8]) {
#pragma unroll
  for (int s = 0; s < 8; ++s) {
    const f32x4 f0 = *reinterpret_cast<const f32x4*>(arow + s * 32);
    const f32x4 f1 = *reinterpret_cast<const f32x4*>(arow + s * 32 + 4);
    short8 v;
    v[0] = bf16r(f0[0]); v[1] = bf16r(f0[1]); v[2] = bf16r(f0[2]); v[3] = bf16r(f0[3]);
    v[4] = bf16r(f1[0]); v[5] = bf16r(f1[1]); v[6] = bf16r(f1[2]); v[7] = bf16r(f1[3]);
    a[s] = v;
  }
}

// A fragments when the source is already bf16 [m][256].
__device__ inline void load_a_bf16(const unsigned short* __restrict__ arow, short8 a[8]) {
#pragma unroll
  for (int s = 0; s < 8; ++s)
    a[s] = *reinterpret_cast<const short8*>(arow + s * 32);
}

// One 16(M)x16(N) output tile over K=256: 8 MFMA steps.
__device__ inline f32x4 tile_mm(const unsigned short* __restrict__ btlane,
                                const short8 a[8]) {
  short8 b[8];
#pragma unroll
  for (int s = 0; s < 8; ++s)
    b[s] = *reinterpret_cast<const short8*>(btlane + s * 32);
  f32x4 acc = {0.f, 0.f, 0.f, 0.f};
#pragma unroll
  for (int s = 0; s < 8; ++s)
    acc = __builtin_amdgcn_mfma_f32_16x16x32_bf16(a[s], b[s], acc, 0, 0, 0);
  return acc;
}

// ---------------------------------------------------------------------------
// Weight prep: LDS-tiled transpose + bf16 convert, W[k][n] -> Bt[n][k].
// ---------------------------------------------------------------------------
__global__ __launch_bounds__(256) void k_prep(
    const float* __restrict__ Wv, const float* __restrict__ Woff,
    const float* __restrict__ Wattn, const float* __restrict__ Wo,
    unsigned short* __restrict__ Btv, unsigned short* __restrict__ Btoa,
    unsigned short* __restrict__ Bto) {
  __shared__ float tile[32][33];
  const int blk = blockIdx.x;
  const float* src; unsigned short* dst; int N, local;
  if (blk < 64)       { src = Wv;    dst = Btv;             N = 256; local = blk; }
  else if (blk < 128) { src = Woff;  dst = Btoa;            N = 256; local = blk - 64; }
  else if (blk < 160) { src = Wattn; dst = Btoa + 256 * 256; N = 128; local = blk - 128; }
  else                { src = Wo;    dst = Bto;             N = 256; local = blk - 160; }
  const int ntiles = N >> 5;
  const int kt = local / ntiles, nt = local - kt * ntiles;
  const int k0 = kt << 5, n0 = nt << 5;
  const int tx = threadIdx.x & 31, ty = threadIdx.x >> 5;
#pragma unroll
  for (int r = 0; r < 4; ++r) {
    const int kk = ty + r * 8;
    tile[kk][tx] = src[(size_t)(k0 + kk) * N + n0 + tx];
  }
  __syncthreads();
#pragma unroll
  for (int r = 0; r < 4; ++r) {
    const int nn = ty + r * 8;
    dst[(size_t)(n0 + nn) * 256 + k0 + tx] = (unsigned short)bf16r(tile[tx][nn]);
  }
}

// ---------------------------------------------------------------------------
// GEMM 1: val = value @ Wv + bv  -> bf16 [B][NH][LV][D]
// ---------------------------------------------------------------------------
__global__ __launch_bounds__(256) void k_gemm_val(
    const float* __restrict__ value, const unsigned short* __restrict__ Bt,
    const float* __restrict__ bv, unsigned short* __restrict__ val) {
  const int wave = (blockIdx.x << 2) + (threadIdx.x >> 6);
  const int lane = threadIdx.x & 63, quad = lane >> 4, lo = lane & 15;
  const int m0 = wave << 4;
  int mr = m0 + lo; if (mr >= M) mr = M - 1;
  const int br = mr / LV, ir = mr - br * LV;
  short8 a[8];
  load_a_f32(value + ((size_t)(ir * B + br)) * C + quad * 8, a);
  const int mbase = m0 + quad * 4;
  for (int t = 0; t < 16; ++t) {
    const int n = t * 16 + lo;
    const f32x4 acc = tile_mm(Bt + (size_t)n * 256 + quad * 8, a);
    const float bias = bv[n];
    const int h = n >> 5, d = n & 31;
#pragma unroll
    for (int r = 0; r < 4; ++r) {
      const int m = mbase + r;
      if (m < M) {
        const int b = m / LV, i = m - b * LV;
        val[(((size_t)(b * NH + h)) * LV + i) * D + d] =
            (unsigned short)bf16r(acc[r] + bias);
      }
    }
  }
}

// ---------------------------------------------------------------------------
// GEMM 2: offsets -> sampling locations; attn logits -> softmaxed weights.
// ---------------------------------------------------------------------------
__global__ __launch_bounds__(256) void k_gemm_offattn(
    const float* __restrict__ query, const float* __restrict__ rp,
    const unsigned short* __restrict__ Bt, const float* __restrict__ boff,
    const float* __restrict__ battn, float* __restrict__ loc,
    float* __restrict__ attn) {
  const int wave = (blockIdx.x << 2) + (threadIdx.x >> 6);
  const int lane = threadIdx.x & 63, quad = lane >> 4, lo = lane & 15;
  const int m0 = wave << 4;
  int mr = m0 + lo; if (mr >= M) mr = M - 1;
  const int br = mr / LQ, qr = mr - br * LQ;
  short8 a[8];
  load_a_f32(query + ((size_t)(qr * B + br)) * C + quad * 8, a);
  const int mbase = m0 + quad * 4;
  for (int t = 0; t < 24; ++t) {
    const int n = t * 16 + lo;
    const f32x4 acc = tile_mm(Bt + (size_t)n * 256 + quad * 8, a);
    if (t < 16) {
      const int xy = n & 1, l = (n >> 3) & 3;
      const float sz = (l == 0) ? 100.f : (l == 1) ? 50.f : (l == 2) ? 25.f : 13.f;
      const float bias = boff[n];
#pragma unroll
      for (int r = 0; r < 4; ++r) {
        const int m = mbase + r;
        if (m < M) {
          float rv = rp[(size_t)m * 8 + l * 2 + xy];
          rv = fminf(fmaxf(rv, 1e-5f), 1.f - 1e-5f);
          loc[(size_t)m * 256 + n] = rv + (acc[r] + bias) / sz;
        }
      }
    } else {
      const int n2 = (t - 16) * 16 + lo;   // head*16 + col
      const float bias = battn[n2];
#pragma unroll
      for (int r = 0; r < 4; ++r) {
        float v = acc[r] + bias;
        float mx = v;
#pragma unroll
        for (int msk = 8; msk >= 1; msk >>= 1) mx = fmaxf(mx, __shfl_xor(mx, msk, 64));
        const float e = __expf(v - mx);
        float s = e;
#pragma unroll
        for (int msk = 8; msk >= 1; msk >>= 1) s += __shfl_xor(s, msk, 64);
        const int m = mbase + r;
        if (m < M) attn[(size_t)m * 128 + n2] = e / s;
      }
    }
  }
}

// ---------------------------------------------------------------------------
// Bilinear sampling + attention weighting, v3.
// Same structure as v2 (8 q/block, 32 threads/q, bf16x8 channel gathers) but
// with controlled unrolling + __launch_bounds__(256,4) to stop the R3
// register blowout (VGPR=256, 11% occupancy, 110 MB of spill traffic).
// ---------------------------------------------------------------------------
__global__ __launch_bounds__(256, 4) void k_sample(
    const unsigned short* __restrict__ val, const float* __restrict__ loc,
    const float* __restrict__ attn, unsigned short* __restrict__ tmp) {
  constexpr int QPB = 8;
  const int mblk = blockIdx.x * QPB;
  const int t = threadIdx.x;
  __shared__ float sloc[QPB * 8 * 33];    // [q][h][33]
  __shared__ float sattn[QPB * 8 * 17];   // [q][h][17]
  for (int i = t; i < QPB * 256; i += 256) {
    int mq = mblk + (i >> 8); if (mq >= M) mq = M - 1;
    const int j = i & 255;
    sloc[(((i >> 8) << 3) + (j >> 5)) * 33 + (j & 31)] = loc[(size_t)mq * 256 + j];
  }
  for (int i = t; i < QPB * 128; i += 256) {
    int mq = mblk + (i >> 7); if (mq >= M) mq = M - 1;
    const int j = i & 127;
    sattn[(((i >> 7) << 3) + (j >> 4)) * 17 + (j & 15)] = attn[(size_t)mq * 128 + j];
  }
  __syncthreads();

  const int g = t >> 5, s = t & 31, h = s >> 2, c8 = s & 3;
  const int m = mblk + g;
  const int mc = (m < M) ? m : M - 1;
  const int b = mc / LQ;
  const unsigned short* vhead = val + ((size_t)(b * NH + h) * LV) * D + c8 * 8;
  const float* ql = sloc + (g * 8 + h) * 33;
  const float* qa = sattn + (g * 8 + h) * 17;

  float acc[8] = {0.f, 0.f, 0.f, 0.f, 0.f, 0.f, 0.f, 0.f};
#pragma unroll 1
  for (int l = 0; l < L; ++l) {
    const int Wl = SZ[l];
    const float Wlf = (float)Wl;
    const unsigned short* vlev = vhead + (size_t)START[l] * D;
#pragma unroll 2
    for (int p = 0; p < P; ++p) {
      const float x = ql[l * 8 + p * 2]     * Wlf - 0.5f;
      const float y = ql[l * 8 + p * 2 + 1] * Wlf - 0.5f;
      const float aw = qa[l * 4 + p];
      const float x0f = floorf(x), y0f = floorf(y);
      const float wx = x - x0f, wy = y - y0f;
      const int x0 = (int)x0f, y0 = (int)y0f;
      const float wy1 = wy * aw, wy0 = aw - wy1;  // aw*(1-wy)
      const float wx1 = wx, wx0 = 1.f - wx;
#pragma unroll
      for (int dy = 0; dy < 2; ++dy) {
#pragma unroll
        for (int dx = 0; dx < 2; ++dx) {
          const int yi = y0 + dy, xi = x0 + dx;
          const bool ok = (xi >= 0) & (xi < Wl) & (yi >= 0) & (yi < Wl);
          const int yc = min(max(yi, 0), Wl - 1);
          const int xc = min(max(xi, 0), Wl - 1);
          const float w = ok ? (dy ? wy1 : wy0) * (dx ? wx1 : wx0) : 0.f;
          const uint4 raw = *reinterpret_cast<const uint4*>(vlev + (yc * Wl + xc) * D);
          acc[0] = fmaf(w, __uint_as_float(raw.x << 16),          acc[0]);
          acc[1] = fmaf(w, __uint_as_float(raw.x & 0xffff0000u),  acc[1]);
          acc[2] = fmaf(w, __uint_as_float(raw.y << 16),          acc[2]);
          acc[3] = fmaf(w, __uint_as_float(raw.y & 0xffff0000u),  acc[3]);
          acc[4] = fmaf(w, __uint_as_float(raw.z << 16),          acc[4]);
          acc[5] = fmaf(w, __uint_as_float(raw.z & 0xffff0000u),  acc[5]);
          acc[6] = fmaf(w, __uint_as_float(raw.w << 16),          acc[6]);
          acc[7] = fmaf(w, __uint_as_float(raw.w & 0xffff0000u),  acc[7]);
        }
      }
    }
  }
  if (m < M) {
    short8 o;
#pragma unroll
    for (int j = 0; j < 8; ++j) o[j] = bf16r(acc[j]);
    *reinterpret_cast<short8*>(tmp + (size_t)m * 256 + h * 32 + c8 * 8) = o;
  }
}

// ---------------------------------------------------------------------------
// GEMM 3: out = tmp @ Wo + bo + query, stored (LQ, B, C). tmp is bf16.
// ---------------------------------------------------------------------------
__global__ __launch_bounds__(256) void k_gemm_out(
    const unsigned short* __restrict__ tmp, const float* __restrict__ query,
    const unsigned short* __restrict__ Bt, const float* __restrict__ bo,
    float* __restrict__ out) {
  const int wave = (blockIdx.x << 2) + (threadIdx.x >> 6);
  const int lane = threadIdx.x & 63, quad = lane >> 4, lo = lane & 15;
  const int m0 = wave << 4;
  int mr = m0 + lo; if (mr >= M) mr = M - 1;
  short8 a[8];
  load_a_bf16(tmp + (size_t)mr * 256 + quad * 8, a);
  const int mbase = m0 + quad * 4;
  for (int t = 0; t < 16; ++t) {
    const int n = t * 16 + lo;
    const f32x4 acc = tile_mm(Bt + (size_t)n * 256 + quad * 8, a);
    const float bias = bo[n];
#pragma unroll
    for (int r = 0; r < 4; ++r) {
      const int m = mbase + r;
      if (m < M) {
        const int b = m / LQ, q = m - b * LQ;
        const size_t o = ((size_t)(q * B + b)) * C + n;
        out[o] = acc[r] + bias + query[o];
      }
    }
  }
}

}  // namespace

extern "C" void kernel_launch(void* const* d_in, const int* in_sizes, int n_in,
                              void* d_out, int out_size, void* d_ws, size_t ws_size,
                              hipStream_t stream) {
  const float* query = (const float*)d_in[0];
  const float* rp    = (const float*)d_in[1];
  const float* value = (const float*)d_in[2];
  const float* Wv    = (const float*)d_in[5];
  const float* bv    = (const float*)d_in[6];
  const float* Woff  = (const float*)d_in[7];
  const float* boff  = (const float*)d_in[8];
  const float* Wattn = (const float*)d_in[9];
  const float* battn = (const float*)d_in[10];
  const float* Wo    = (const float*)d_in[11];
  const float* bo    = (const float*)d_in[12];
  float* out = (float*)d_out;

  unsigned short* Btv  = (unsigned short*)d_ws;        // 256*256
  unsigned short* Btoa = Btv + 256 * 256;              // 384*256
  unsigned short* Bto  = Btoa + 384 * 256;             // 256*256
  unsigned short* val  = Bto + 256 * 256;              // B*NH*LV*D bf16
  float* loc  = (float*)(val + (size_t)B * NH * LV * D);  // M*256 f32
  float* attn = loc + (size_t)M * 256;                 // M*128 f32
  unsigned short* tmp = (unsigned short*)(attn + (size_t)M * 128);  // M*256 bf16

  const int gemm_blocks = (M + 63) / 64;               // 416
  const int sample_blocks = (M + 7) / 8;               // 3324

  k_prep<<<224, 256, 0, stream>>>(Wv, Woff, Wattn, Wo, Btv, Btoa, Bto);
  k_gemm_val<<<gemm_blocks, 256, 0, stream>>>(value, Btv, bv, val);
  k_gemm_offattn<<<gemm_blocks, 256, 0, stream>>>(query, rp, Btoa, boff, battn, loc, attn);
  k_sample<<<sample_blocks, 256, 0, stream>>>(val, loc, attn, tmp);
  k_gemm_out<<<gemm_blocks, 256, 0, stream>>>(tmp, query, Bto, bo, out);
}

// Round 5
// 286.087 us; speedup vs baseline: 3.8982x; 1.1180x over previous
//
#include <hip/hip_runtime.h>
#include <math.h>

namespace {

typedef __attribute__((ext_vector_type(8))) short short8;
typedef __attribute__((ext_vector_type(4))) float f32x4;

constexpr int B  = 2;
constexpr int C  = 256;
constexpr int NH = 8;
constexpr int L  = 4;
constexpr int P  = 4;
constexpr int D  = 32;
constexpr int LV = 13294;
constexpr int LQ = 13294;
constexpr int M  = B * LQ;      // 26588 rows for all GEMMs

constexpr int SZ[4]    = {100, 50, 25, 13};
constexpr int START[4] = {0, 10000, 12500, 13125};

__device__ inline short bf16r(float f) {    // RTNE f32 -> bf16
  unsigned u = __float_as_uint(f);
  u += 0x7fff + ((u >> 16) & 1);
  return (short)(u >> 16);
}

__device__ inline void load_a_bf16(const unsigned short* __restrict__ arow, short8 a[8]) {
#pragma unroll
  for (int s = 0; s < 8; ++s)
    a[s] = *reinterpret_cast<const short8*>(arow + s * 32);
}

// ---------------------------------------------------------------------------
// Convert+transpose query/value (len,B,C) f32 -> [m][256] bf16 (m = b*len+i).
// One wave per row; 4 elements/thread. grid = 2*M/4 blocks of 256.
// ---------------------------------------------------------------------------
__global__ __launch_bounds__(256) void k_cvt(
    const float* __restrict__ query, const float* __restrict__ value,
    unsigned short* __restrict__ qbf, unsigned short* __restrict__ vbf) {
  const int gid = blockIdx.x * 256 + threadIdx.x;
  const int rid = gid >> 6;              // row id over 2*M
  if (rid >= 2 * M) return;
  const int c4 = (gid & 63) * 4;
  const int tensor = (rid >= M) ? 1 : 0;
  const int m = tensor ? rid - M : rid;
  const int b = m / LQ, i = m - b * LQ;
  const float* src = (tensor ? value : query) + ((size_t)(i * B + b)) * C + c4;
  const f32x4 f = *reinterpret_cast<const f32x4*>(src);
  unsigned short* dst = (tensor ? vbf : qbf) + (size_t)m * C + c4;
  ushort2 lo, hi;
  lo.x = (unsigned short)bf16r(f[0]); lo.y = (unsigned short)bf16r(f[1]);
  hi.x = (unsigned short)bf16r(f[2]); hi.y = (unsigned short)bf16r(f[3]);
  uint2 o;
  o.x = (unsigned)lo.x | ((unsigned)lo.y << 16);
  o.y = (unsigned)hi.x | ((unsigned)hi.y << 16);
  *reinterpret_cast<uint2*>(dst) = o;
}

// ---------------------------------------------------------------------------
// Weight prep: LDS-tiled transpose + bf16 convert, W[k][n] -> Bt[n][k].
// ---------------------------------------------------------------------------
__global__ __launch_bounds__(256) void k_prep(
    const float* __restrict__ Wv, const float* __restrict__ Woff,
    const float* __restrict__ Wattn, const float* __restrict__ Wo,
    unsigned short* __restrict__ Btv, unsigned short* __restrict__ Btoa,
    unsigned short* __restrict__ Bto) {
  __shared__ float tile[32][33];
  const int blk = blockIdx.x;
  const float* src; unsigned short* dst; int N, local;
  if (blk < 64)       { src = Wv;    dst = Btv;             N = 256; local = blk; }
  else if (blk < 128) { src = Woff;  dst = Btoa;            N = 256; local = blk - 64; }
  else if (blk < 160) { src = Wattn; dst = Btoa + 256 * 256; N = 128; local = blk - 128; }
  else                { src = Wo;    dst = Bto;             N = 256; local = blk - 160; }
  const int ntiles = N >> 5;
  const int kt = local / ntiles, nt = local - kt * ntiles;
  const int k0 = kt << 5, n0 = nt << 5;
  const int tx = threadIdx.x & 31, ty = threadIdx.x >> 5;
#pragma unroll
  for (int r = 0; r < 4; ++r) {
    const int kk = ty + r * 8;
    tile[kk][tx] = src[(size_t)(k0 + kk) * N + n0 + tx];
  }
  __syncthreads();
#pragma unroll
  for (int r = 0; r < 4; ++r) {
    const int nn = ty + r * 8;
    dst[(size_t)(n0 + nn) * 256 + k0 + tx] = (unsigned short)bf16r(tile[tx][nn]);
  }
}

// ---------------------------------------------------------------------------
// GEMM core: one 64-thread block = one wave computing 32 M-rows x 64 N-cols.
// grid = (ceil(M/32), N/64). A pre-converted bf16 [m][256]; B-frags reused
// across the 2 A-sets (4x less B traffic than R4's 16-row waves).
// ---------------------------------------------------------------------------

// GEMM 1: val = vbf @ Wv + bv -> bf16 [B][NH][LV][D]
__global__ __launch_bounds__(64) void k_gemm_val(
    const unsigned short* __restrict__ Abf, const unsigned short* __restrict__ Bt,
    const float* __restrict__ bv, unsigned short* __restrict__ val) {
  const int lane = threadIdx.x, quad = lane >> 4, lo = lane & 15;
  const int m0 = blockIdx.x * 32;
  const int n0 = blockIdx.y * 64;
  const int mr0 = min(m0 + lo, M - 1), mr1 = min(m0 + 16 + lo, M - 1);
  short8 a0[8], a1[8];
  load_a_bf16(Abf + (size_t)mr0 * 256 + quad * 8, a0);
  load_a_bf16(Abf + (size_t)mr1 * 256 + quad * 8, a1);
#pragma unroll 1
  for (int t = 0; t < 4; ++t) {
    const int n = n0 + t * 16 + lo;
    const unsigned short* bt = Bt + (size_t)n * 256 + quad * 8;
    short8 b[8];
#pragma unroll
    for (int s = 0; s < 8; ++s) b[s] = *reinterpret_cast<const short8*>(bt + s * 32);
    f32x4 acc0 = {0.f, 0.f, 0.f, 0.f}, acc1 = acc0;
#pragma unroll
    for (int s = 0; s < 8; ++s) {
      acc0 = __builtin_amdgcn_mfma_f32_16x16x32_bf16(a0[s], b[s], acc0, 0, 0, 0);
      acc1 = __builtin_amdgcn_mfma_f32_16x16x32_bf16(a1[s], b[s], acc1, 0, 0, 0);
    }
    const float bias = bv[n];
    const int h = n >> 5, d = n & 31;
#pragma unroll
    for (int r = 0; r < 4; ++r) {
      const int ma = m0 + quad * 4 + r, mb = ma + 16;
      if (ma < M) {
        const int bb = ma / LV, i = ma - bb * LV;
        val[(((size_t)(bb * NH + h)) * LV + i) * D + d] = (unsigned short)bf16r(acc0[r] + bias);
      }
      if (mb < M) {
        const int bb = mb / LV, i = mb - bb * LV;
        val[(((size_t)(bb * NH + h)) * LV + i) * D + d] = (unsigned short)bf16r(acc1[r] + bias);
      }
    }
  }
}

// GEMM 2: offsets -> sampling locations; attn logits -> softmaxed weights.
// Global N-tiles 0..15 = offsets, 16..23 = attn heads. grid.y = 6 (x64 cols).
__global__ __launch_bounds__(64) void k_gemm_offattn(
    const unsigned short* __restrict__ Abf, const float* __restrict__ rp,
    const unsigned short* __restrict__ Bt, const float* __restrict__ boff,
    const float* __restrict__ battn, float* __restrict__ loc,
    float* __restrict__ attn) {
  const int lane = threadIdx.x, quad = lane >> 4, lo = lane & 15;
  const int m0 = blockIdx.x * 32;
  const int mr0 = min(m0 + lo, M - 1), mr1 = min(m0 + 16 + lo, M - 1);
  short8 a0[8], a1[8];
  load_a_bf16(Abf + (size_t)mr0 * 256 + quad * 8, a0);
  load_a_bf16(Abf + (size_t)mr1 * 256 + quad * 8, a1);
#pragma unroll 1
  for (int tt = 0; tt < 4; ++tt) {
    const int t = blockIdx.y * 4 + tt;   // global 16-wide tile id, 0..23
    const int n = t * 16 + lo;
    const unsigned short* bt = Bt + (size_t)n * 256 + quad * 8;
    short8 b[8];
#pragma unroll
    for (int s = 0; s < 8; ++s) b[s] = *reinterpret_cast<const short8*>(bt + s * 32);
    f32x4 acc0 = {0.f, 0.f, 0.f, 0.f}, acc1 = acc0;
#pragma unroll
    for (int s = 0; s < 8; ++s) {
      acc0 = __builtin_amdgcn_mfma_f32_16x16x32_bf16(a0[s], b[s], acc0, 0, 0, 0);
      acc1 = __builtin_amdgcn_mfma_f32_16x16x32_bf16(a1[s], b[s], acc1, 0, 0, 0);
    }
    if (t < 16) {
      const int xy = n & 1, l = (n >> 3) & 3;
      const float sz = (l == 0) ? 100.f : (l == 1) ? 50.f : (l == 2) ? 25.f : 13.f;
      const float bias = boff[n];
#pragma unroll
      for (int half = 0; half < 2; ++half) {
        const f32x4& acc = half ? acc1 : acc0;
#pragma unroll
        for (int r = 0; r < 4; ++r) {
          const int m = m0 + half * 16 + quad * 4 + r;
          if (m < M) {
            float rv = rp[(size_t)m * 8 + l * 2 + xy];
            rv = fminf(fmaxf(rv, 1e-5f), 1.f - 1e-5f);
            loc[(size_t)m * 256 + n] = rv + (acc[r] + bias) / sz;
          }
        }
      }
    } else {
      const int n2 = (t - 16) * 16 + lo;   // head*16 + col
      const float bias = battn[n2];
#pragma unroll
      for (int half = 0; half < 2; ++half) {
        const f32x4& acc = half ? acc1 : acc0;
#pragma unroll
        for (int r = 0; r < 4; ++r) {
          float v = acc[r] + bias;
          float mx = v;
#pragma unroll
          for (int msk = 8; msk >= 1; msk >>= 1) mx = fmaxf(mx, __shfl_xor(mx, msk, 64));
          const float e = __expf(v - mx);
          float s = e;
#pragma unroll
          for (int msk = 8; msk >= 1; msk >>= 1) s += __shfl_xor(s, msk, 64);
          const int m = m0 + half * 16 + quad * 4 + r;
          if (m < M) attn[(size_t)m * 128 + n2] = e / s;
        }
      }
    }
  }
}

// GEMM 3: out = tmp @ Wo + bo + query, stored (LQ, B, C). tmp bf16.
__global__ __launch_bounds__(64) void k_gemm_out(
    const unsigned short* __restrict__ tmp, const float* __restrict__ query,
    const unsigned short* __restrict__ Bt, const float* __restrict__ bo,
    float* __restrict__ out) {
  const int lane = threadIdx.x, quad = lane >> 4, lo = lane & 15;
  const int m0 = blockIdx.x * 32;
  const int n0 = blockIdx.y * 64;
  const int mr0 = min(m0 + lo, M - 1), mr1 = min(m0 + 16 + lo, M - 1);
  short8 a0[8], a1[8];
  load_a_bf16(tmp + (size_t)mr0 * 256 + quad * 8, a0);
  load_a_bf16(tmp + (size_t)mr1 * 256 + quad * 8, a1);
#pragma unroll 1
  for (int t = 0; t < 4; ++t) {
    const int n = n0 + t * 16 + lo;
    const unsigned short* bt = Bt + (size_t)n * 256 + quad * 8;
    short8 b[8];
#pragma unroll
    for (int s = 0; s < 8; ++s) b[s] = *reinterpret_cast<const short8*>(bt + s * 32);
    f32x4 acc0 = {0.f, 0.f, 0.f, 0.f}, acc1 = acc0;
#pragma unroll
    for (int s = 0; s < 8; ++s) {
      acc0 = __builtin_amdgcn_mfma_f32_16x16x32_bf16(a0[s], b[s], acc0, 0, 0, 0);
      acc1 = __builtin_amdgcn_mfma_f32_16x16x32_bf16(a1[s], b[s], acc1, 0, 0, 0);
    }
    const float bias = bo[n];
#pragma unroll
    for (int r = 0; r < 4; ++r) {
      const int ma = m0 + quad * 4 + r, mb = ma + 16;
      if (ma < M) {
        const int bb = ma / LQ, q = ma - bb * LQ;
        const size_t o = ((size_t)(q * B + bb)) * C + n;
        out[o] = acc0[r] + bias + query[o];
      }
      if (mb < M) {
        const int bb = mb / LQ, q = mb - bb * LQ;
        const size_t o = ((size_t)(q * B + bb)) * C + n;
        out[o] = acc1[r] + bias + query[o];
      }
    }
  }
}

// ---------------------------------------------------------------------------
// Bilinear sampling + attention weighting (R4 version — at VMEM issue limit).
// ---------------------------------------------------------------------------
__global__ __launch_bounds__(256, 4) void k_sample(
    const unsigned short* __restrict__ val, const float* __restrict__ loc,
    const float* __restrict__ attn, unsigned short* __restrict__ tmp) {
  constexpr int QPB = 8;
  const int mblk = blockIdx.x * QPB;
  const int t = threadIdx.x;
  __shared__ float sloc[QPB * 8 * 33];    // [q][h][33]
  __shared__ float sattn[QPB * 8 * 17];   // [q][h][17]
  for (int i = t; i < QPB * 256; i += 256) {
    int mq = mblk + (i >> 8); if (mq >= M) mq = M - 1;
    const int j = i & 255;
    sloc[(((i >> 8) << 3) + (j >> 5)) * 33 + (j & 31)] = loc[(size_t)mq * 256 + j];
  }
  for (int i = t; i < QPB * 128; i += 256) {
    int mq = mblk + (i >> 7); if (mq >= M) mq = M - 1;
    const int j = i & 127;
    sattn[(((i >> 7) << 3) + (j >> 4)) * 17 + (j & 15)] = attn[(size_t)mq * 128 + j];
  }
  __syncthreads();

  const int g = t >> 5, s = t & 31, h = s >> 2, c8 = s & 3;
  const int m = mblk + g;
  const int mc = (m < M) ? m : M - 1;
  const int b = mc / LQ;
  const unsigned short* vhead = val + ((size_t)(b * NH + h) * LV) * D + c8 * 8;
  const float* ql = sloc + (g * 8 + h) * 33;
  const float* qa = sattn + (g * 8 + h) * 17;

  float acc[8] = {0.f, 0.f, 0.f, 0.f, 0.f, 0.f, 0.f, 0.f};
#pragma unroll 1
  for (int l = 0; l < L; ++l) {
    const int Wl = SZ[l];
    const float Wlf = (float)Wl;
    const unsigned short* vlev = vhead + (size_t)START[l] * D;
#pragma unroll 2
    for (int p = 0; p < P; ++p) {
      const float x = ql[l * 8 + p * 2]     * Wlf - 0.5f;
      const float y = ql[l * 8 + p * 2 + 1] * Wlf - 0.5f;
      const float aw = qa[l * 4 + p];
      const float x0f = floorf(x), y0f = floorf(y);
      const float wx = x - x0f, wy = y - y0f;
      const int x0 = (int)x0f, y0 = (int)y0f;
      const float wy1 = wy * aw, wy0 = aw - wy1;  // aw*(1-wy)
      const float wx1 = wx, wx0 = 1.f - wx;
#pragma unroll
      for (int dy = 0; dy < 2; ++dy) {
#pragma unroll
        for (int dx = 0; dx < 2; ++dx) {
          const int yi = y0 + dy, xi = x0 + dx;
          const bool ok = (xi >= 0) & (xi < Wl) & (yi >= 0) & (yi < Wl);
          const int yc = min(max(yi, 0), Wl - 1);
          const int xc = min(max(xi, 0), Wl - 1);
          const float w = ok ? (dy ? wy1 : wy0) * (dx ? wx1 : wx0) : 0.f;
          const uint4 raw = *reinterpret_cast<const uint4*>(vlev + (yc * Wl + xc) * D);
          acc[0] = fmaf(w, __uint_as_float(raw.x << 16),          acc[0]);
          acc[1] = fmaf(w, __uint_as_float(raw.x & 0xffff0000u),  acc[1]);
          acc[2] = fmaf(w, __uint_as_float(raw.y << 16),          acc[2]);
          acc[3] = fmaf(w, __uint_as_float(raw.y & 0xffff0000u),  acc[3]);
          acc[4] = fmaf(w, __uint_as_float(raw.z << 16),          acc[4]);
          acc[5] = fmaf(w, __uint_as_float(raw.z & 0xffff0000u),  acc[5]);
          acc[6] = fmaf(w, __uint_as_float(raw.w << 16),          acc[6]);
          acc[7] = fmaf(w, __uint_as_float(raw.w & 0xffff0000u),  acc[7]);
        }
      }
    }
  }
  if (m < M) {
    short8 o;
#pragma unroll
    for (int j = 0; j < 8; ++j) o[j] = bf16r(acc[j]);
    *reinterpret_cast<short8*>(tmp + (size_t)m * 256 + h * 32 + c8 * 8) = o;
  }
}

}  // namespace

extern "C" void kernel_launch(void* const* d_in, const int* in_sizes, int n_in,
                              void* d_out, int out_size, void* d_ws, size_t ws_size,
                              hipStream_t stream) {
  const float* query = (const float*)d_in[0];
  const float* rp    = (const float*)d_in[1];
  const float* value = (const float*)d_in[2];
  const float* Wv    = (const float*)d_in[5];
  const float* bv    = (const float*)d_in[6];
  const float* Woff  = (const float*)d_in[7];
  const float* boff  = (const float*)d_in[8];
  const float* Wattn = (const float*)d_in[9];
  const float* battn = (const float*)d_in[10];
  const float* Wo    = (const float*)d_in[11];
  const float* bo    = (const float*)d_in[12];
  float* out = (float*)d_out;

  unsigned short* Btv  = (unsigned short*)d_ws;        // 256*256
  unsigned short* Btoa = Btv + 256 * 256;              // 384*256
  unsigned short* Bto  = Btoa + 384 * 256;             // 256*256
  unsigned short* qbf  = Bto + 256 * 256;              // M*256 bf16
  unsigned short* vbf  = qbf + (size_t)M * 256;        // M*256 bf16
  unsigned short* val  = vbf + (size_t)M * 256;        // M*256 bf16
  float* loc  = (float*)(val + (size_t)M * 256);       // M*256 f32
  float* attn = loc + (size_t)M * 256;                 // M*128 f32
  unsigned short* tmp = vbf;   // alias: vbf consumed by k_gemm_val before k_sample

  const int mtiles = (M + 31) / 32;                    // 831
  const int sample_blocks = (M + 7) / 8;               // 3324

  k_cvt<<<(2 * M + 3) / 4, 256, 0, stream>>>(query, value, qbf, vbf);
  k_prep<<<224, 256, 0, stream>>>(Wv, Woff, Wattn, Wo, Btv, Btoa, Bto);
  k_gemm_val<<<dim3(mtiles, 4), 64, 0, stream>>>(vbf, Btv, bv, val);
  k_gemm_offattn<<<dim3(mtiles, 6), 64, 0, stream>>>(qbf, rp, Btoa, boff, battn, loc, attn);
  k_sample<<<sample_blocks, 256, 0, stream>>>(val, loc, attn, tmp);
  k_gemm_out<<<dim3(mtiles, 4), 64, 0, stream>>>(tmp, query, Bto, bo, out);
}